// Round 3
// baseline (143.787 us; speedup 1.0000x reference)
//
#include <hip/hip_runtime.h>

namespace {
constexpr int B = 16, C = 19, H = 512, W = 512;
constexpr int TPB = 128;                     // thread t owns cols 4t..4t+3 (covers full W)
constexpr int H_CHUNK = 64;
constexpr int NHC = H / H_CHUNK;             // 8
constexpr int TILES = B * NHC;               // 128 (b,hc) tiles
constexpr int NXCD = 8;
constexpr int TILES_PER_XCD = TILES / NXCD;  // 16
constexpr int TOTAL_BLOCKS = TILES * C;      // 2432
constexpr float SCALE = 1.0f / (float)((long long)B * H * W);
}

// Per-row separable-Sobel aggregates for 4 owned columns:
//   d[j] = x[j+1]-x[j-1], s[j] = x[j-1]+2x[j]+x[j+1]; md/ms same for one-hot mask.
// Then gx = d(h-1)+2d(h)+d(h+1), gy = s(h+1)-s(h-1).
struct RowS { float4 d, s, md, ms; };

__global__ void zero_out_kernel(float* out) { *out = 0.0f; }

__global__ __launch_bounds__(TPB) void edge_loss_kernel(
    const float* __restrict__ X,   // [B,C,H,W] f32
    const int*   __restrict__ T,   // [B,H,W] int32 labels
    float* __restrict__ out)
{
    // XCD swizzle: hardware round-robins bid%8; put all 19 c-blocks of one
    // (b,hc) tile on ONE XCD so its target tile is L2-fetched once.
    int i = (int)blockIdx.x;
    const int xcd  = i & (NXCD - 1);
    const int j    = i >> 3;
    const int c    = j % C;
    const int tl   = j / C;
    const int tile = xcd * TILES_PER_XCD + tl;
    const int b    = tile / NHC;
    const int hc   = tile % NHC;

    const int tid = (int)threadIdx.x;
    const int w0  = tid << 2;
    const int h0  = hc * H_CHUNK;

    const float* __restrict__ Xs = X + (size_t)(b * C + c) * (size_t)(H * W);
    const int*   __restrict__ Ts = T + (size_t)b * (size_t)(H * W);

    // halo columns: clamped address + 0/1 border mask, uniform control flow
    const int   wm = (w0 > 0)     ? (w0 - 1) : 0;
    const int   wp = (w0 + 4 < W) ? (w0 + 4) : (W - 1);
    const float fl = (w0 > 0)     ? 1.0f : 0.0f;
    const float fr = (w0 + 4 < W) ? 1.0f : 0.0f;

    RowS r0, r1, r2;
    float acc = 0.0f;

    auto zero_row = [&](RowS& r) {
        r.d = r.s = r.md = r.ms = make_float4(0.f, 0.f, 0.f, 0.f);
    };

    auto load_row = [&](RowS& r, const float* xrow, const int* trow) {
        const float4 xv = *reinterpret_cast<const float4*>(xrow + w0);
        const int4   tv = *reinterpret_cast<const int4*>(trow + w0);
        const float xl = xrow[wm] * fl;                    // L1 hits: lines already
        const float xh = xrow[wp] * fr;                    // fetched by vector loads
        const float ml = (trow[wm] == c) ? fl : 0.0f;
        const float mh = (trow[wp] == c) ? fr : 0.0f;

        const float m0 = (tv.x == c) ? 1.0f : 0.0f;
        const float m1 = (tv.y == c) ? 1.0f : 0.0f;
        const float m2 = (tv.z == c) ? 1.0f : 0.0f;
        const float m3 = (tv.w == c) ? 1.0f : 0.0f;

        r.d.x = xv.y - xl;   r.d.y = xv.z - xv.x;
        r.d.z = xv.w - xv.y; r.d.w = xh   - xv.z;
        r.s.x = fmaf(2.f, xv.x, xl   + xv.y);
        r.s.y = fmaf(2.f, xv.y, xv.x + xv.z);
        r.s.z = fmaf(2.f, xv.z, xv.y + xv.w);
        r.s.w = fmaf(2.f, xv.w, xv.z + xh);

        r.md.x = m1 - ml; r.md.y = m2 - m0;
        r.md.z = m3 - m1; r.md.w = mh - m2;
        r.ms.x = fmaf(2.f, m0, ml + m1);
        r.ms.y = fmaf(2.f, m1, m0 + m2);
        r.ms.z = fmaf(2.f, m2, m1 + m3);
        r.ms.w = fmaf(2.f, m3, m2 + mh);
    };

    auto comp = [&](const RowS& ra, const RowS& rb, const RowS& rc) {
#define COMP(f)                                                  \
        {                                                        \
            const float gx = fmaf(2.f, rb.d.f,  ra.d.f  + rc.d.f); \
            const float gy = rc.s.f  - ra.s.f;                   \
            const float hx = fmaf(2.f, rb.md.f, ra.md.f + rc.md.f); \
            const float hy = rc.ms.f - ra.ms.f;                  \
            const float dd = (fabsf(gx) + fabsf(gy))             \
                           - (fabsf(hx) + fabsf(hy));            \
            acc = fmaf(dd, dd, acc);                             \
        }
        COMP(x) COMP(y) COMP(z) COMP(w)
#undef COMP
    };

    const float* xrow = Xs + (size_t)h0 * W;
    const int*   trow = Ts + (size_t)h0 * W;

    // prologue: rows h0-1 (block-uniform check) and h0 (always valid)
    if (hc == 0) zero_row(r0);
    else         load_row(r0, xrow - W, trow - W);
    load_row(r1, xrow, trow);

    // 63 branch-free steps: rows h0+1..h0+63 are always in range
#define STEP(ra, rb, rc)                        \
    {                                           \
        xrow += W; trow += W;                   \
        load_row(rc, xrow, trow);               \
        comp(ra, rb, rc);                       \
    }
    for (int t = 0; t < 21; ++t) {              // 21*3 = 63 rows: h0..h0+62
        STEP(r0, r1, r2)
        STEP(r1, r2, r0)
        STEP(r2, r0, r1)
    }
#undef STEP
    // final output row h0+63 needs row h0+64 (OOB only for hc == NHC-1)
    if (hc == NHC - 1) zero_row(r2);
    else {
        xrow += W; trow += W;
        load_row(r2, xrow, trow);
    }
    comp(r0, r1, r2);

    // reduce: wave shuffle, 2 waves via LDS, one atomic per block
    #pragma unroll
    for (int off = 32; off > 0; off >>= 1)
        acc += __shfl_down(acc, off, 64);

    __shared__ float wsum[TPB / 64];
    const int lane = tid & 63;
    const int wid  = tid >> 6;
    if (lane == 0) wsum[wid] = acc;
    __syncthreads();
    if (tid == 0) atomicAdd(out, (wsum[0] + wsum[1]) * SCALE);
}

extern "C" void kernel_launch(void* const* d_in, const int* in_sizes, int n_in,
                              void* d_out, int out_size, void* d_ws, size_t ws_size,
                              hipStream_t stream) {
    (void)in_sizes; (void)n_in; (void)d_ws; (void)ws_size; (void)out_size;
    const float* X = (const float*)d_in[0];
    const int*   T = (const int*)d_in[1];
    float* out = (float*)d_out;

    zero_out_kernel<<<1, 1, 0, stream>>>(out);
    edge_loss_kernel<<<TOTAL_BLOCKS, TPB, 0, stream>>>(X, T, out);
}

// Round 4
// 109.543 us; speedup vs baseline: 1.3126x; 1.3126x over previous
//
#include <hip/hip_runtime.h>

namespace {
constexpr int B = 16, C = 19, H = 512, W = 512;
constexpr int TPB = 256;                     // one column per thread (R1 geometry)
constexpr int H_CHUNK = 128;
constexpr int NWB = W / TPB;                 // 2
constexpr int NHC = H / H_CHUNK;             // 4
constexpr int NXCD = 8;
constexpr int TILES = B * NHC * NWB;         // 128 (b,hc,wb) target tiles
constexpr int TILES_PER_XCD = TILES / NXCD;  // 16
constexpr int TOTAL_BLOCKS = TILES * C;      // 2432 (= 8 * 304, swizzle bijective)
constexpr float SCALE = 1.0f / (float)((long long)B * H * W);
}

__global__ void zero_out_kernel(float* out) { *out = 0.0f; }

__global__ __launch_bounds__(TPB) void edge_loss_kernel(
    const float* __restrict__ X,   // [B,C,H,W] f32
    const int*   __restrict__ T,   // [B,H,W] int32 labels
    float* __restrict__ out)
{
    // XCD swizzle: consecutive blockIdx round-robin across 8 XCD L2s (bid%8).
    // Group all 19 class-blocks of one (b,hc,wb) target tile on ONE XCD,
    // adjacent in dispatch order -> T tile is L2-resident, fetched ~once.
    int i = (int)blockIdx.x;
    const int xcd  = i & (NXCD - 1);
    const int j    = i >> 3;
    const int c    = j % C;                    // fastest within XCD slot order
    const int tl   = j / C;
    const int tile = xcd * TILES_PER_XCD + tl;
    const int wb   = tile & 1;
    const int hc   = (tile >> 1) & 3;
    const int b    = tile >> 3;

    const int tid = (int)threadIdx.x;
    const int w   = wb * TPB + tid;            // global column 0..511
    const int h0  = hc * H_CHUNK;

    const float* __restrict__ Xs = X + (size_t)(b * C + c) * (size_t)(H * W);
    const int*   __restrict__ Ts = T + (size_t)b * (size_t)(H * W);

    // column halo: clamped index + 0/1 border factor (branchless, coalesced)
    const int   wm = (w > 0)     ? (w - 1) : 0;
    const int   wp = (w < W - 1) ? (w + 1) : (W - 1);
    const float fl = (w > 0)     ? 1.0f : 0.0f;
    const float fr = (w < W - 1) ? 1.0f : 0.0f;

    // Separable Sobel row aggregates (per owned column):
    //   d = x[w+1]-x[w-1]          -> gx = d(h-1) + 2 d(h) + d(h+1)
    //   s = x[w-1]+2x[w]+x[w+1]    -> gy = s(h+1) - s(h-1)
    //   e,u: same for the one-hot mask (t == c)
    const float* xr = Xs + (size_t)h0 * W;
    const int*   tr = Ts + (size_t)h0 * W;

    auto ldrow = [&](const float* xrow, const int* trow,
                     float& d, float& s, float& e, float& u) {
        const float xm = xrow[wm] * fl;
        const float x0 = xrow[w];
        const float xp = xrow[wp] * fr;
        const int   ta = trow[wm];
        const int   t0 = trow[w];
        const int   tb = trow[wp];
        const float mm = (ta == c) ? fl : 0.0f;
        const float m0 = (t0 == c) ? 1.0f : 0.0f;
        const float mp = (tb == c) ? fr : 0.0f;
        d = xp - xm;
        s = fmaf(2.0f, x0, xm + xp);
        e = mp - mm;
        u = fmaf(2.0f, m0, mm + mp);
    };

    float d0,s0,e0,u0, d1,s1,e1,u1, d2,s2,e2,u2;
    float acc = 0.0f;

#define COMPUTE(dA,sA,eA,uA, dB,sB,eB,uB, dC,sC,eC,uC)          \
    {                                                           \
        const float gx = fmaf(2.0f, dB, dA + dC);               \
        const float gy = sC - sA;                               \
        const float hx = fmaf(2.0f, eB, eA + eC);               \
        const float hy = uC - uA;                               \
        const float dd = (fabsf(gx) + fabsf(gy))                \
                       - (fabsf(hx) + fabsf(hy));               \
        acc = fmaf(dd, dd, acc);                                \
    }
#define BODY(dA,sA,eA,uA, dB,sB,eB,uB, dC,sC,eC,uC)             \
    {                                                           \
        xr += W; tr += W;                                       \
        ldrow(xr, tr, dC, sC, eC, uC);                          \
        COMPUTE(dA,sA,eA,uA, dB,sB,eB,uB, dC,sC,eC,uC)          \
    }

    // prologue: row h0-1 (block-uniform check) and row h0
    if (hc == 0) { d0 = s0 = e0 = u0 = 0.0f; }
    else         ldrow(xr - W, tr - W, d0, s0, e0, u0);
    ldrow(xr, tr, d1, s1, e1, u1);

    // 42 branch-free triples: outputs h0 .. h0+125 (rows h0+1..h0+126 loaded)
    for (int t = 0; t < 42; ++t) {
        BODY(d0,s0,e0,u0, d1,s1,e1,u1, d2,s2,e2,u2)   // out h0+3t
        BODY(d1,s1,e1,u1, d2,s2,e2,u2, d0,s0,e0,u0)   // out h0+3t+1
        BODY(d2,s2,e2,u2, d0,s0,e0,u0, d1,s1,e1,u1)   // out h0+3t+2
    }
    // output h0+126 (loads row h0+127, always in range)
    BODY(d0,s0,e0,u0, d1,s1,e1,u1, d2,s2,e2,u2)
    // output h0+127 (needs row h0+128; OOB only for the last h-chunk)
    if (hc == NHC - 1) { d0 = s0 = e0 = u0 = 0.0f; }
    else { xr += W; tr += W; ldrow(xr, tr, d0, s0, e0, u0); }
    COMPUTE(d1,s1,e1,u1, d2,s2,e2,u2, d0,s0,e0,u0)

#undef BODY
#undef COMPUTE

    // reduce: wave shuffle -> LDS across 4 waves -> one atomic per block
    #pragma unroll
    for (int off = 32; off > 0; off >>= 1)
        acc += __shfl_down(acc, off, 64);

    __shared__ float wsum[TPB / 64];
    const int lane = tid & 63;
    const int wid  = tid >> 6;
    if (lane == 0) wsum[wid] = acc;
    __syncthreads();
    if (tid == 0)
        atomicAdd(out, (wsum[0] + wsum[1] + wsum[2] + wsum[3]) * SCALE);
}

extern "C" void kernel_launch(void* const* d_in, const int* in_sizes, int n_in,
                              void* d_out, int out_size, void* d_ws, size_t ws_size,
                              hipStream_t stream) {
    (void)in_sizes; (void)n_in; (void)d_ws; (void)ws_size; (void)out_size;
    const float* X = (const float*)d_in[0];
    const int*   T = (const int*)d_in[1];
    float* out = (float*)d_out;

    zero_out_kernel<<<1, 1, 0, stream>>>(out);
    edge_loss_kernel<<<TOTAL_BLOCKS, TPB, 0, stream>>>(X, T, out);
}